// Round 2
// baseline (2102.528 us; speedup 1.0000x reference)
//
#include <hip/hip_runtime.h>
#include <hip/hip_fp16.h>
#include <cstdint>

#define NLAYERS 4
#define TILE_E 32
#define GT_NODES 8

__device__ __forceinline__ float silu_f(float x){ return x / (1.f + __expf(-x)); }

// ---------------- init: h_s = embed[z], h_v=h_t=0, deg=0, readout accumulators ----------------
__global__ void k_init(const int* __restrict__ z, const float* __restrict__ embed,
                       float* __restrict__ hs, float* __restrict__ hv, float* __restrict__ ht,
                       int* __restrict__ deg,
                       unsigned* __restrict__ mkey, float* __restrict__ den, float* __restrict__ cbuf,
                       int N, int G){
  int idx = blockIdx.x*blockDim.x + threadIdx.x;
  if (idx < N*64) hs[idx] = embed[z[idx>>6]*64 + (idx&63)];
  if (idx < N*96) hv[idx] = 0.f;
  if (idx < N*80) ht[idx] = 0.f;
  if (idx < N)   deg[idx] = 0;
  if (idx < G) { mkey[idx] = 0u; den[idx] = 0.f; }
  if (idx < G*64) cbuf[idx] = 0.f;
}

// ---------------- per-edge static features: rb (10) and Y (9) ----------------
__global__ void k_efeat(const float* __restrict__ pos, const int* __restrict__ src,
                        const int* __restrict__ dst,
                        float* __restrict__ rbbuf, float* __restrict__ ybuf, int E){
  int e = blockIdx.x*blockDim.x + threadIdx.x;
  if (e >= E) return;
  int s = src[e], d = dst[e];
  float vx = pos[d*3+0]-pos[s*3+0];
  float vy = pos[d*3+1]-pos[s*3+1];
  float vz = pos[d*3+2]-pos[s*3+2];
  float elen = sqrtf(vx*vx+vy*vy+vz*vz);
  float inv = 1.f/(elen+1e-9f);
  float x = vx*inv, y = vy*inv, zc = vz*inv;
  const float s3 = 1.7320508075688772f, s5 = 2.2360679774997896f, s15 = 3.872983346207417f;
  ybuf[e*9+0] = 1.f;
  ybuf[e*9+1] = s3*x;  ybuf[e*9+2] = s3*y;  ybuf[e*9+3] = s3*zc;
  ybuf[e*9+4] = s15*x*y; ybuf[e*9+5] = s15*y*zc;
  ybuf[e*9+6] = 0.5f*s5*(3.f*zc*zc-1.f);
  ybuf[e*9+7] = s15*x*zc; ybuf[e*9+8] = 0.5f*s15*(x*x-y*y);
  const float sigma = 5.0f/9.0f;
  #pragma unroll
  for (int k=0;k<10;k++){
    float c = (5.0f/9.0f)*(float)k;
    float t = (elen - c)/sigma;
    rbbuf[e*10+k] = __expf(-0.5f*t*t);
  }
}

// ---------------- CSR build ----------------
__global__ void k_deg(const int* __restrict__ dst, int* __restrict__ deg, int E){
  int e = blockIdx.x*blockDim.x + threadIdx.x;
  if (e < E) atomicAdd(&deg[dst[e]], 1);
}

__global__ __launch_bounds__(256) void k_scan(const int* __restrict__ deg, int* __restrict__ rowptr,
                                              int* __restrict__ cursor, int N){
  __shared__ int part[256];
  int t = threadIdx.x;
  int chunk = (N + 255)/256;
  int lo = t*chunk, hi = min(N, lo+chunk);
  int s = 0;
  for (int n=lo;n<hi;n++) s += deg[n];
  part[t] = s;
  __syncthreads();
  if (t==0){
    int run = 0;
    for (int i=0;i<256;i++){ int v = part[i]; part[i] = run; run += v; }
  }
  __syncthreads();
  int run = part[t];
  for (int n=lo;n<hi;n++){ rowptr[n]=run; cursor[n]=run; run += deg[n]; }
  if (lo < N && hi == N) rowptr[N] = run;
}

__global__ void k_fill(const int* __restrict__ dst, int* __restrict__ cursor,
                       int* __restrict__ eidx, int E){
  int e = blockIdx.x*blockDim.x + threadIdx.x;
  if (e < E){
    int pos = atomicAdd(&cursor[dst[e]], 1);
    eidx[pos] = e;
  }
}

// ---------------- k_wgt: per-edge radial weights, materialized fp16 ----------------
__global__ __launch_bounds__(320) void k_wgt(
    const float* __restrict__ rbbuf,
    const float* __restrict__ rW1, const float* __restrict__ rb1, const float* __restrict__ rW2,
    __half* __restrict__ wgtbuf, int E, int l)
{
  __shared__ float hid[TILE_E][32];
  int t = threadIdx.x;
  int e0 = blockIdx.x*TILE_E;

  for (int idx=t; idx<TILE_E*32; idx+=320){
    int el = idx>>5, j = idx&31;
    int e = e0+el;
    if (e < E){
      float acc = rb1[l*32+j];
      const float* rbp = rbbuf + (size_t)e*10;
      const float* w1p = rW1 + (l*10)*32 + j;
      #pragma unroll
      for (int k=0;k<10;k++) acc += rbp[k]*w1p[k*32];
      hid[el][j] = silu_f(acc);
    }
  }
  float wcol[32];
  {
    const float* w2p = rW2 + (size_t)(l*32)*320 + t;
    #pragma unroll
    for (int j=0;j<32;j++) wcol[j] = w2p[(size_t)j*320];
  }
  __syncthreads();

  for (int el=0; el<TILE_E; el++){
    int e = e0+el;
    if (e >= E) break;
    float acc = 0.f;
    #pragma unroll
    for (int j=0;j<32;j++) acc += hid[el][j]*wcol[j];
    wgtbuf[(size_t)e*320 + t] = __float2half(acc);
  }
}

// ---------------- k_gather: CSR gather of messages + fused node update ----------------
__global__ __launch_bounds__(256) void k_gather(
    const float* __restrict__ hs0, const float* __restrict__ hv0, const float* __restrict__ ht0,
    float* __restrict__ hs1, float* __restrict__ hv1, float* __restrict__ ht1,
    const int* __restrict__ rowptr, const int* __restrict__ eidx, const int* __restrict__ srcArr,
    const float* __restrict__ ybuf, const __half* __restrict__ wgtbuf,
    const float* __restrict__ Ws, const float* __restrict__ Wss,
    const float* __restrict__ Wv, const float* __restrict__ Wvv,
    const float* __restrict__ Wt, const float* __restrict__ Wtt,
    int N, int l)
{
  __shared__ float acc[GT_NODES][896];   // flat: [0,112) a0, [112,496) a1, [496,896) a2
  __shared__ float hold[GT_NODES][240];  // old h of dst nodes: [0,64) s, [64,160) v, [160,240) t
  int t = threadIdx.x, w = t>>6, lane = t&63;
  int n0 = blockIdx.x*GT_NODES;
  int nmax = min(GT_NODES, N-n0);

  for (int idx=t; idx<nmax*240; idx+=256){
    int n = idx/240, c = idx - n*240;
    float v;
    if (c < 64)       v = hs0[(size_t)(n0+n)*64 + c];
    else if (c < 160) v = hv0[(size_t)(n0+n)*96 + (c-64)];
    else              v = ht0[(size_t)(n0+n)*80 + (c-160)];
    hold[n][c] = v;
  }

  // aggregation: wave w owns node slots w and w+4; no atomics, no block barriers
  for (int sub=0; sub<2; sub++){
    int slot = w + sub*4;
    int n = n0 + slot;
    if (n < N){
      int rs = rowptr[n], re = rowptr[n+1];
      float r[14];
      #pragma unroll
      for (int k=0;k<14;k++) r[k] = 0.f;
      for (int j=rs; j<re; j++){
        int e  = eidx[j];
        int s_ = srcArr[e];
        const float* pS = hs0 + (size_t)s_*64;
        const float* pV = hv0 + (size_t)s_*96;
        const float* pT = ht0 + (size_t)s_*80;
        const float* pY = ybuf + (size_t)e*9;
        const __half* wp = wgtbuf + (size_t)e*320;
        #pragma unroll
        for (int k=0;k<14;k++){
          int c = k*64 + lane;
          float val;
          if (c < 112){
            float wg = __half2float(wp[c]);
            if (c < 64) val = wg * pS[c];
            else if (c < 96){
              int cc = c-64;
              val = wg * (pV[cc*3+0]*pY[1] + pV[cc*3+1]*pY[2] + pV[cc*3+2]*pY[3]);
            } else {
              int cc = c-96;
              float a = 0.f;
              #pragma unroll
              for (int d2=0; d2<5; d2++) a += pT[cc*5+d2]*pY[4+d2];
              val = wg * a;
            }
          } else if (c < 496){
            int rr = c-112;
            int row = rr/3, dd = rr - row*3;
            if (row < 64)      val = __half2float(wp[112+row]) * pS[row] * pY[1+dd];
            else if (row < 96) val = __half2float(wp[176+(row-64)]) * pV[(row-64)*3+dd];
            else {
              int cc = row-96;
              int d1 = dd+1; if (d1>2) d1-=3;
              int d2 = dd+2; if (d2>2) d2-=3;
              val = __half2float(wp[208+cc]) * (pV[cc*3+d1]*pY[1+d2] - pV[cc*3+d2]*pY[1+d1]);
            }
          } else {
            int rr = c-496;
            int row = rr/5, dd = rr - row*5;
            if (row < 64) val = __half2float(wp[240+row]) * pS[row] * pY[4+dd];
            else          val = __half2float(wp[304+(row-64)]) * pT[(row-64)*5+dd];
          }
          r[k] += val;
        }
      }
      #pragma unroll
      for (int k=0;k<14;k++) acc[slot][k*64+lane] = r[k];
    }
  }
  __syncthreads();

  // fused node update (old k_node), reading LDS acc + hold
  float ua[GT_NODES];
  #pragma unroll
  for (int n=0;n<GT_NODES;n++) ua[n] = 0.f;

  if (t < 64){
    int f = t;
    for (int c=0;c<112;c++){
      float wv_ = Ws[((size_t)l*112+c)*64+f];
      #pragma unroll
      for (int n=0;n<GT_NODES;n++) ua[n] += acc[n][c]*wv_;
    }
    for (int c=0;c<64;c++){
      float wv_ = Wss[((size_t)l*64+c)*64+f];
      #pragma unroll
      for (int n=0;n<GT_NODES;n++) ua[n] += hold[n][c]*wv_;
    }
    for (int n=0;n<nmax;n++) hs1[(size_t)(n0+n)*64+f] = silu_f(ua[n]);
  } else if (t < 160){
    int rr = t-64, f = rr/3, dd = rr - f*3;
    for (int c=0;c<128;c++){
      float wv_ = Wv[((size_t)l*128+c)*32+f];
      #pragma unroll
      for (int n=0;n<GT_NODES;n++) ua[n] += acc[n][112+c*3+dd]*wv_;
    }
    for (int c=0;c<32;c++){
      float wv_ = Wvv[((size_t)l*32+c)*32+f];
      #pragma unroll
      for (int n=0;n<GT_NODES;n++) ua[n] += hold[n][64+c*3+dd]*wv_;
    }
    for (int n=0;n<nmax;n++) hv1[(size_t)(n0+n)*96+f*3+dd] = ua[n];
  } else if (t < 240){
    int rr = t-160, f = rr/5, dd = rr - f*5;
    for (int c=0;c<80;c++){
      float wv_ = Wt[((size_t)l*80+c)*16+f];
      #pragma unroll
      for (int n=0;n<GT_NODES;n++) ua[n] += acc[n][496+c*5+dd]*wv_;
    }
    for (int c=0;c<16;c++){
      float wv_ = Wtt[((size_t)l*16+c)*16+f];
      #pragma unroll
      for (int n=0;n<GT_NODES;n++) ua[n] += hold[n][160+c*5+dd]*wv_;
    }
    for (int n=0;n<nmax;n++) ht1[(size_t)(n0+n)*80+f*5+dd] = ua[n];
  }
}

// ---------------- readout ----------------
__global__ __launch_bounds__(64) void k_q(const float* __restrict__ hs, const int* __restrict__ absorber,
                                          const float* __restrict__ Wq, float* __restrict__ qbuf, int G){
  __shared__ float sH[64];
  int g = blockIdx.x, f = threadIdx.x;
  int a = absorber[g];
  sH[f] = hs[(size_t)a*64+f];
  __syncthreads();
  float acc = 0.f;
  for (int c=0;c<64;c++) acc += sH[c]*Wq[c*64+f];
  qbuf[(size_t)g*64+f] = acc;
}

__global__ __launch_bounds__(64) void k_kv(const float* __restrict__ hs,
                                           const float* __restrict__ Wk, const float* __restrict__ Wvp,
                                           float* __restrict__ kbuf, float* __restrict__ vbuf, int N){
  __shared__ float sH[8][64];
  int t = threadIdx.x;
  int n0 = blockIdx.x*8;
  int nmax = min(8, N-n0);
  for (int idx=t; idx<nmax*64; idx+=64){ int n=idx>>6, c=idx&63; sH[n][c]=hs[(size_t)(n0+n)*64+c]; }
  __syncthreads();
  float ka[8], va[8];
  #pragma unroll
  for (int n=0;n<8;n++){ ka[n]=0.f; va[n]=0.f; }
  for (int c=0;c<64;c++){
    float wk = Wk[c*64+t], wv = Wvp[c*64+t];
    #pragma unroll
    for (int n=0;n<8;n++){ ka[n]+=sH[n][c]*wk; va[n]+=sH[n][c]*wv; }
  }
  for (int n=0;n<nmax;n++){ kbuf[(size_t)(n0+n)*64+t]=ka[n]; vbuf[(size_t)(n0+n)*64+t]=va[n]; }
}

__global__ __launch_bounds__(256) void k_logit(const float* __restrict__ kbuf, const float* __restrict__ qbuf,
                                               const int* __restrict__ batch,
                                               float* __restrict__ logitbuf, unsigned* __restrict__ mkey, int N){
  int wave = threadIdx.x>>6, lane = threadIdx.x&63;
  int n = blockIdx.x*4 + wave;
  if (n >= N) return;
  int g = batch[n];
  float p = kbuf[(size_t)n*64+lane]*qbuf[(size_t)g*64+lane];
  #pragma unroll
  for (int off=32; off>0; off>>=1) p += __shfl_down(p, off, 64);
  if (lane==0){
    float logit = p*0.125f;
    logitbuf[n] = logit;
    unsigned u = __float_as_uint(logit);
    unsigned key = (u & 0x80000000u) ? ~u : (u | 0x80000000u);
    atomicMax(&mkey[g], key);
  }
}

__global__ __launch_bounds__(256) void k_soft(const float* __restrict__ vbuf, const float* __restrict__ logitbuf,
                                              const int* __restrict__ batch, const unsigned* __restrict__ mkey,
                                              float* __restrict__ den, float* __restrict__ cbuf, int N){
  int wave = threadIdx.x>>6, lane = threadIdx.x&63;
  int n = blockIdx.x*4 + wave;
  if (n >= N) return;
  int g = batch[n];
  unsigned key = mkey[g];
  unsigned u = (key & 0x80000000u) ? (key ^ 0x80000000u) : ~key;
  float m = __uint_as_float(u);
  float ex = __expf(logitbuf[n] - m);
  if (lane==0) atomicAdd(&den[g], ex);
  atomicAdd(&cbuf[(size_t)g*64+lane], ex*vbuf[(size_t)n*64+lane]);
}

__global__ __launch_bounds__(192) void k_final(const float* __restrict__ hs, const float* __restrict__ hv,
                                               const float* __restrict__ ht, const int* __restrict__ absorber,
                                               const float* __restrict__ den, const float* __restrict__ cbuf,
                                               const float* __restrict__ Wr1, const float* __restrict__ br1,
                                               const float* __restrict__ Wr2, const float* __restrict__ br2,
                                               float* __restrict__ out, int G){
  __shared__ float zr[176];
  __shared__ float h1[128];
  int g = blockIdx.x, t = threadIdx.x;
  int a = absorber[g];
  if (t < 64) zr[t] = hs[(size_t)a*64+t];
  else if (t < 128){
    int f = t-64;
    zr[t] = cbuf[(size_t)g*64+f] / fmaxf(den[g], 1e-9f);
  } else if (t < 160){
    int j = t-128; float s = 0.f;
    #pragma unroll
    for (int dd=0;dd<3;dd++){ float v = hv[(size_t)a*96+j*3+dd]; s += v*v; }
    zr[t] = s;
  } else if (t < 176){
    int j = t-160; float s = 0.f;
    #pragma unroll
    for (int dd=0;dd<5;dd++){ float v = ht[(size_t)a*80+j*5+dd]; s += v*v; }
    zr[t] = s;
  }
  __syncthreads();
  if (t < 128){
    float acc = br1[t];
    for (int i=0;i<176;i++) acc += zr[i]*Wr1[i*128+t];
    h1[t] = silu_f(acc);
  }
  __syncthreads();
  if (t < 128){
    float acc = br2[t];
    for (int j=0;j<128;j++) acc += h1[j]*Wr2[j*128+t];
    out[(size_t)g*128+t] = acc;
  }
}

extern "C" void kernel_launch(void* const* d_in, const int* in_sizes, int n_in,
                              void* d_out, int out_size, void* d_ws, size_t ws_size,
                              hipStream_t stream){
  const int*   z        = (const int*)  d_in[0];
  const float* pos      = (const float*)d_in[1];
  const int*   ei       = (const int*)  d_in[2];
  const int*   batch    = (const int*)  d_in[3];
  const int*   absorber = (const int*)  d_in[4];
  const float* embed    = (const float*)d_in[5];
  const float* rW1      = (const float*)d_in[6];
  const float* rb1      = (const float*)d_in[7];
  const float* rW2      = (const float*)d_in[8];
  const float* Ws       = (const float*)d_in[9];
  const float* Wss      = (const float*)d_in[10];
  const float* Wv       = (const float*)d_in[11];
  const float* Wvv      = (const float*)d_in[12];
  const float* Wt       = (const float*)d_in[13];
  const float* Wtt      = (const float*)d_in[14];
  const float* Wq       = (const float*)d_in[15];
  const float* Wk       = (const float*)d_in[16];
  const float* Wvp      = (const float*)d_in[17];
  const float* Wr1      = (const float*)d_in[18];
  const float* br1      = (const float*)d_in[19];
  const float* Wr2      = (const float*)d_in[20];
  const float* br2      = (const float*)d_in[21];

  int N = in_sizes[0];
  int E = in_sizes[2]/2;
  int G = in_sizes[4];
  const int* srcArr = ei;
  const int* dstArr = ei + E;

  float* p = (float*)d_ws;
  float* hsA   = p; p += (size_t)N*64;
  float* hvA   = p; p += (size_t)N*96;
  float* htA   = p; p += (size_t)N*80;
  float* hsB   = p; p += (size_t)N*64;
  float* hvB   = p; p += (size_t)N*96;
  float* htB   = p; p += (size_t)N*80;
  float* rbbuf = p; p += (size_t)E*10;
  float* ybuf  = p; p += (size_t)E*9;
  unsigned* mkey = (unsigned*)p; p += G;
  float* den   = p; p += G;
  float* cbuf  = p; p += (size_t)G*64;
  int* deg     = (int*)p; p += N;
  int* rowptr  = (int*)p; p += (N+1);
  int* cursor  = (int*)p; p += N;
  int* eidx    = (int*)p; p += E;
  // wgt buffer (fp16), reused per layer; readout f32 buffers alias it (used after layers)
  __half* wgtbuf = (__half*)p;
  float* kbuf    = (float*)wgtbuf;
  float* vbuf    = kbuf + (size_t)N*64;
  float* qbuf    = vbuf + (size_t)N*64;
  float* logitbuf= qbuf + (size_t)G*64;

  int initTot = N*96;
  k_init<<<(initTot+255)/256, 256, 0, stream>>>(z, embed, hsA, hvA, htA, deg, mkey, den, cbuf, N, G);
  k_efeat<<<(E+255)/256, 256, 0, stream>>>(pos, srcArr, dstArr, rbbuf, ybuf, E);
  k_deg<<<(E+255)/256, 256, 0, stream>>>(dstArr, deg, E);
  k_scan<<<1, 256, 0, stream>>>(deg, rowptr, cursor, N);
  k_fill<<<(E+255)/256, 256, 0, stream>>>(dstArr, cursor, eidx, E);

  float *hsO=hsA, *hvO=hvA, *htO=htA, *hsN=hsB, *hvN=hvB, *htN=htB;
  for (int l=0; l<NLAYERS; l++){
    k_wgt<<<(E+TILE_E-1)/TILE_E, 320, 0, stream>>>(rbbuf, rW1, rb1, rW2, wgtbuf, E, l);
    k_gather<<<(N+GT_NODES-1)/GT_NODES, 256, 0, stream>>>(hsO, hvO, htO, hsN, hvN, htN,
                                                          rowptr, eidx, srcArr, ybuf, wgtbuf,
                                                          Ws, Wss, Wv, Wvv, Wt, Wtt, N, l);
    float* tp;
    tp=hsO; hsO=hsN; hsN=tp;
    tp=hvO; hvO=hvN; hvN=tp;
    tp=htO; htO=htN; htN=tp;
  }

  k_q<<<G, 64, 0, stream>>>(hsO, absorber, Wq, qbuf, G);
  k_kv<<<(N+7)/8, 64, 0, stream>>>(hsO, Wk, Wvp, kbuf, vbuf, N);
  k_logit<<<(N+3)/4, 256, 0, stream>>>(kbuf, qbuf, batch, logitbuf, mkey, N);
  k_soft<<<(N+3)/4, 256, 0, stream>>>(vbuf, logitbuf, batch, mkey, den, cbuf, N);
  k_final<<<G, 192, 0, stream>>>(hsO, hvO, htO, absorber, den, cbuf, Wr1, br1, Wr2, br2, (float*)d_out, G);
}

// Round 3
// 1682.795 us; speedup vs baseline: 1.2494x; 1.2494x over previous
//
#include <hip/hip_runtime.h>
#include <hip/hip_fp16.h>
#include <cstdint>

#define NLAYERS 4
#define TILE_E 32
#define GT_NODES 8

__device__ __forceinline__ float silu_f(float x){ return x / (1.f + __expf(-x)); }

// ---------------- init ----------------
__global__ void k_init(const int* __restrict__ z, const float* __restrict__ embed,
                       float* __restrict__ hs, float* __restrict__ hv, float* __restrict__ ht,
                       int* __restrict__ deg,
                       unsigned* __restrict__ mkey, float* __restrict__ den, float* __restrict__ cbuf,
                       int N, int G){
  int idx = blockIdx.x*blockDim.x + threadIdx.x;
  if (idx < N*64) hs[idx] = embed[z[idx>>6]*64 + (idx&63)];
  if (idx < N*96) hv[idx] = 0.f;
  if (idx < N*80) ht[idx] = 0.f;
  if (idx < N)   deg[idx] = 0;
  if (idx < G) { mkey[idx] = 0u; den[idx] = 0.f; }
  if (idx < G*64) cbuf[idx] = 0.f;
}

// ---------------- CSR build ----------------
__global__ void k_deg(const int* __restrict__ dst, int* __restrict__ deg, int E){
  int e = blockIdx.x*blockDim.x + threadIdx.x;
  if (e < E) atomicAdd(&deg[dst[e]], 1);
}

__global__ __launch_bounds__(256) void k_scanA(const int* __restrict__ deg, int* __restrict__ bsum, int N){
  __shared__ int red[256];
  int t = threadIdx.x;
  int idx = blockIdx.x*256 + t;
  red[t] = (idx < N) ? deg[idx] : 0;
  __syncthreads();
  for (int off=128; off>0; off>>=1){ if (t<off) red[t] += red[t+off]; __syncthreads(); }
  if (t==0) bsum[blockIdx.x] = red[0];
}

__global__ __launch_bounds__(256) void k_scanB(const int* __restrict__ bsum, int* __restrict__ boff, int nb){
  __shared__ int s[256];
  int t = threadIdx.x;
  s[t] = (t < nb) ? bsum[t] : 0;
  __syncthreads();
  for (int off=1; off<256; off<<=1){
    int v = (t>=off) ? s[t-off] : 0;
    __syncthreads();
    s[t] += v;
    __syncthreads();
  }
  if (t < nb) boff[t] = (t==0) ? 0 : s[t-1];
}

__global__ __launch_bounds__(256) void k_scanC(const int* __restrict__ deg, const int* __restrict__ boff,
                                               int* __restrict__ rowptr, int* __restrict__ cursor, int N){
  __shared__ int s[256];
  int t = threadIdx.x;
  int idx = blockIdx.x*256 + t;
  int v = (idx < N) ? deg[idx] : 0;
  s[t] = v;
  __syncthreads();
  for (int off=1; off<256; off<<=1){
    int u = (t>=off) ? s[t-off] : 0;
    __syncthreads();
    s[t] += u;
    __syncthreads();
  }
  int base = boff[blockIdx.x];
  if (idx < N){
    int ex = base + s[t] - v;
    rowptr[idx] = ex;
    cursor[idx] = ex;
    if (idx == N-1) rowptr[N] = base + s[t];
  }
}

__global__ void k_fill(const int* __restrict__ dst, const int* __restrict__ src,
                       int* __restrict__ cursor, int* __restrict__ inv, int* __restrict__ src_sorted, int E){
  int e = blockIdx.x*blockDim.x + threadIdx.x;
  if (e < E){
    int p = atomicAdd(&cursor[dst[e]], 1);
    inv[e] = p;
    src_sorted[p] = src[e];
  }
}

// ---------------- edge features, written in CSR position order ----------------
__global__ void k_efeat(const float* __restrict__ pos, const int* __restrict__ src,
                        const int* __restrict__ dst, const int* __restrict__ inv,
                        float* __restrict__ rb_csr, float* __restrict__ y_csr, int E){
  int e = blockIdx.x*blockDim.x + threadIdx.x;
  if (e >= E) return;
  int s = src[e], d = dst[e];
  int j = inv[e];
  float vx = pos[d*3+0]-pos[s*3+0];
  float vy = pos[d*3+1]-pos[s*3+1];
  float vz = pos[d*3+2]-pos[s*3+2];
  float elen = sqrtf(vx*vx+vy*vy+vz*vz);
  float iv = 1.f/(elen+1e-9f);
  float x = vx*iv, y = vy*iv, zc = vz*iv;
  const float s3 = 1.7320508075688772f, s5 = 2.2360679774997896f, s15 = 3.872983346207417f;
  // y_csr stores Y[1..8] (Y[0]==1 implicit), stride 8
  float* yp = y_csr + (size_t)j*8;
  yp[0] = s3*x;  yp[1] = s3*y;  yp[2] = s3*zc;
  yp[3] = s15*x*y; yp[4] = s15*y*zc;
  yp[5] = 0.5f*s5*(3.f*zc*zc-1.f);
  yp[6] = s15*x*zc; yp[7] = 0.5f*s15*(x*x-y*y);
  const float sigma = 5.0f/9.0f;
  float* rp = rb_csr + (size_t)j*10;
  #pragma unroll
  for (int k=0;k<10;k++){
    float c = (5.0f/9.0f)*(float)k;
    float tt = (elen - c)/sigma;
    rp[k] = __expf(-0.5f*tt*tt);
  }
}

// ---------------- k_wgt: radial weights in CSR order, fp16 ----------------
__global__ __launch_bounds__(320) void k_wgt(
    const float* __restrict__ rb_csr,
    const float* __restrict__ rW1, const float* __restrict__ rb1, const float* __restrict__ rW2,
    __half* __restrict__ wgtbuf, int E, int l)
{
  __shared__ float hid[TILE_E][32];
  int t = threadIdx.x;
  int j0 = blockIdx.x*TILE_E;

  for (int idx=t; idx<TILE_E*32; idx+=320){
    int el = idx>>5, jj = idx&31;
    int j = j0+el;
    if (j < E){
      float acc = rb1[l*32+jj];
      const float* rbp = rb_csr + (size_t)j*10;
      const float* w1p = rW1 + (l*10)*32 + jj;
      #pragma unroll
      for (int k=0;k<10;k++) acc += rbp[k]*w1p[k*32];
      hid[el][jj] = silu_f(acc);
    }
  }
  float wcol[32];
  {
    const float* w2p = rW2 + (size_t)(l*32)*320 + t;
    #pragma unroll
    for (int jj=0;jj<32;jj++) wcol[jj] = w2p[(size_t)jj*320];
  }
  __syncthreads();

  for (int el=0; el<TILE_E; el++){
    int j = j0+el;
    if (j >= E) break;
    const float4* hrow = (const float4*)hid[el];
    float a0=0.f,a1=0.f,a2=0.f,a3=0.f;
    #pragma unroll
    for (int q=0;q<8;q++){
      float4 h4 = hrow[q];
      a0 += h4.x*wcol[q*4+0];
      a1 += h4.y*wcol[q*4+1];
      a2 += h4.z*wcol[q*4+2];
      a3 += h4.w*wcol[q*4+3];
    }
    wgtbuf[(size_t)j*320 + t] = __float2half((a0+a1)+(a2+a3));
  }
}

// ---------------- k_gather: one wave per node, streaming CSR operands, fused update ----------------
__global__ __launch_bounds__(512, 4) void k_gather(
    const float* __restrict__ hs0, const float* __restrict__ hv0, const float* __restrict__ ht0,
    float* __restrict__ hs1, float* __restrict__ hv1, float* __restrict__ ht1,
    const int* __restrict__ rowptr, const int* __restrict__ src_sorted,
    const float* __restrict__ y_csr, const __half* __restrict__ wgtbuf,
    const float* __restrict__ Ws, const float* __restrict__ Wss,
    const float* __restrict__ Wv, const float* __restrict__ Wvv,
    const float* __restrict__ Wt, const float* __restrict__ Wtt,
    int N, int l)
{
  __shared__ float acc[GT_NODES][896];   // [0,112) a0, [112,496) a1, [496,896) a2
  __shared__ float hold[GT_NODES][240];  // [0,64) s, [64,160) v, [160,240) t
  int t = threadIdx.x, w = t>>6, lane = t&63;
  int n0 = blockIdx.x*GT_NODES;
  int nmax = min(GT_NODES, N-n0);

  for (int idx=t; idx<nmax*240; idx+=512){
    int n = idx/240, c = idx - n*240;
    float v;
    if (c < 64)       v = hs0[(size_t)(n0+n)*64 + c];
    else if (c < 160) v = hv0[(size_t)(n0+n)*96 + (c-64)];
    else              v = ht0[(size_t)(n0+n)*80 + (c-160)];
    hold[n][c] = v;
  }

  int n = n0 + w;
  float r[14];
  #pragma unroll
  for (int k=0;k<14;k++) r[k] = 0.f;

  if (n < N){
    int rs = rowptr[n], re = rowptr[n+1];
    for (int j=rs; j<re; j++){
      int s_ = src_sorted[j];
      const float* pS = hs0 + (size_t)s_*64;
      const float* pV = hv0 + (size_t)s_*96;
      const float* pT = ht0 + (size_t)s_*80;
      const float4* pY4 = (const float4*)(y_csr + (size_t)j*8);
      float4 ya = pY4[0], yb = pY4[1];
      float y1=ya.x, y2=ya.y, y3=ya.z, y4=ya.w, y5=yb.x, y6=yb.y, y7=yb.z, y8=yb.w;
      const __half* wp = wgtbuf + (size_t)j*320;
      #pragma unroll
      for (int k=0;k<14;k++){
        int c = k*64 + lane;
        float val;
        if (c < 112){
          float wg = __half2float(wp[c]);
          if (c < 64) val = wg * pS[c];
          else if (c < 96){
            int cc = c-64;
            val = wg * (pV[cc*3+0]*y1 + pV[cc*3+1]*y2 + pV[cc*3+2]*y3);
          } else {
            int cc = c-96;
            val = wg * (pT[cc*5+0]*y4 + pT[cc*5+1]*y5 + pT[cc*5+2]*y6 + pT[cc*5+3]*y7 + pT[cc*5+4]*y8);
          }
        } else if (c < 496){
          int rr = c-112;
          int row = rr/3, dd = rr - row*3;
          if (row < 64){
            float yd = dd==0 ? y1 : (dd==1 ? y2 : y3);
            val = __half2float(wp[112+row]) * pS[row] * yd;
          } else if (row < 96){
            val = __half2float(wp[176+(row-64)]) * pV[(row-64)*3+dd];
          } else {
            int cc = row-96;
            int d1 = dd+1; if (d1>2) d1-=3;
            int d2 = dd+2; if (d2>2) d2-=3;
            float yd2 = d2==0 ? y1 : (d2==1 ? y2 : y3);
            float yd1 = d1==0 ? y1 : (d1==1 ? y2 : y3);
            val = __half2float(wp[208+cc]) * (pV[cc*3+d1]*yd2 - pV[cc*3+d2]*yd1);
          }
        } else {
          int rr = c-496;
          int row = rr/5, dd = rr - row*5;
          if (row < 64){
            float yd = dd==0 ? y4 : (dd==1 ? y5 : (dd==2 ? y6 : (dd==3 ? y7 : y8)));
            val = __half2float(wp[240+row]) * pS[row] * yd;
          } else {
            val = __half2float(wp[304+(row-64)]) * pT[(row-64)*5+dd];
          }
        }
        r[k] += val;
      }
    }
    #pragma unroll
    for (int k=0;k<14;k++) acc[w][k*64+lane] = r[k];
  }
  __syncthreads();

  // fused node update
  float ua[GT_NODES];
  #pragma unroll
  for (int nn=0;nn<GT_NODES;nn++) ua[nn] = 0.f;

  if (t < 64){
    int f = t;
    for (int c=0;c<112;c++){
      float wv_ = Ws[((size_t)l*112+c)*64+f];
      #pragma unroll
      for (int nn=0;nn<GT_NODES;nn++) ua[nn] += acc[nn][c]*wv_;
    }
    for (int c=0;c<64;c++){
      float wv_ = Wss[((size_t)l*64+c)*64+f];
      #pragma unroll
      for (int nn=0;nn<GT_NODES;nn++) ua[nn] += hold[nn][c]*wv_;
    }
    for (int nn=0;nn<nmax;nn++) hs1[(size_t)(n0+nn)*64+f] = silu_f(ua[nn]);
  } else if (t < 160){
    int rr = t-64, f = rr/3, dd = rr - f*3;
    for (int c=0;c<128;c++){
      float wv_ = Wv[((size_t)l*128+c)*32+f];
      #pragma unroll
      for (int nn=0;nn<GT_NODES;nn++) ua[nn] += acc[nn][112+c*3+dd]*wv_;
    }
    for (int c=0;c<32;c++){
      float wv_ = Wvv[((size_t)l*32+c)*32+f];
      #pragma unroll
      for (int nn=0;nn<GT_NODES;nn++) ua[nn] += hold[nn][64+c*3+dd]*wv_;
    }
    for (int nn=0;nn<nmax;nn++) hv1[(size_t)(n0+nn)*96+f*3+dd] = ua[nn];
  } else if (t < 240){
    int rr = t-160, f = rr/5, dd = rr - f*5;
    for (int c=0;c<80;c++){
      float wv_ = Wt[((size_t)l*80+c)*16+f];
      #pragma unroll
      for (int nn=0;nn<GT_NODES;nn++) ua[nn] += acc[nn][496+c*5+dd]*wv_;
    }
    for (int c=0;c<16;c++){
      float wv_ = Wtt[((size_t)l*16+c)*16+f];
      #pragma unroll
      for (int nn=0;nn<GT_NODES;nn++) ua[nn] += hold[nn][160+c*5+dd]*wv_;
    }
    for (int nn=0;nn<nmax;nn++) ht1[(size_t)(n0+nn)*80+f*5+dd] = ua[nn];
  }
}

// ---------------- readout ----------------
__global__ __launch_bounds__(64) void k_q(const float* __restrict__ hs, const int* __restrict__ absorber,
                                          const float* __restrict__ Wq, float* __restrict__ qbuf, int G){
  __shared__ float sH[64];
  int g = blockIdx.x, f = threadIdx.x;
  int a = absorber[g];
  sH[f] = hs[(size_t)a*64+f];
  __syncthreads();
  float acc = 0.f;
  for (int c=0;c<64;c++) acc += sH[c]*Wq[c*64+f];
  qbuf[(size_t)g*64+f] = acc;
}

__global__ __launch_bounds__(64) void k_kv(const float* __restrict__ hs,
                                           const float* __restrict__ Wk, const float* __restrict__ Wvp,
                                           float* __restrict__ kbuf, float* __restrict__ vbuf, int N){
  __shared__ float sH[8][64];
  int t = threadIdx.x;
  int n0 = blockIdx.x*8;
  int nmax = min(8, N-n0);
  for (int idx=t; idx<nmax*64; idx+=64){ int n=idx>>6, c=idx&63; sH[n][c]=hs[(size_t)(n0+n)*64+c]; }
  __syncthreads();
  float ka[8], va[8];
  #pragma unroll
  for (int n=0;n<8;n++){ ka[n]=0.f; va[n]=0.f; }
  for (int c=0;c<64;c++){
    float wk = Wk[c*64+t], wv = Wvp[c*64+t];
    #pragma unroll
    for (int n=0;n<8;n++){ ka[n]+=sH[n][c]*wk; va[n]+=sH[n][c]*wv; }
  }
  for (int n=0;n<nmax;n++){ kbuf[(size_t)(n0+n)*64+t]=ka[n]; vbuf[(size_t)(n0+n)*64+t]=va[n]; }
}

__global__ __launch_bounds__(256) void k_logit(const float* __restrict__ kbuf, const float* __restrict__ qbuf,
                                               const int* __restrict__ batch,
                                               float* __restrict__ logitbuf, unsigned* __restrict__ mkey, int N){
  int wave = threadIdx.x>>6, lane = threadIdx.x&63;
  int n = blockIdx.x*4 + wave;
  if (n >= N) return;
  int g = batch[n];
  float p = kbuf[(size_t)n*64+lane]*qbuf[(size_t)g*64+lane];
  #pragma unroll
  for (int off=32; off>0; off>>=1) p += __shfl_down(p, off, 64);
  if (lane==0){
    float logit = p*0.125f;
    logitbuf[n] = logit;
    unsigned u = __float_as_uint(logit);
    unsigned key = (u & 0x80000000u) ? ~u : (u | 0x80000000u);
    atomicMax(&mkey[g], key);
  }
}

__global__ __launch_bounds__(256) void k_soft(const float* __restrict__ vbuf, const float* __restrict__ logitbuf,
                                              const int* __restrict__ batch, const unsigned* __restrict__ mkey,
                                              float* __restrict__ den, float* __restrict__ cbuf, int N){
  int wave = threadIdx.x>>6, lane = threadIdx.x&63;
  int n = blockIdx.x*4 + wave;
  if (n >= N) return;
  int g = batch[n];
  unsigned key = mkey[g];
  unsigned u = (key & 0x80000000u) ? (key ^ 0x80000000u) : ~key;
  float m = __uint_as_float(u);
  float ex = __expf(logitbuf[n] - m);
  if (lane==0) atomicAdd(&den[g], ex);
  atomicAdd(&cbuf[(size_t)g*64+lane], ex*vbuf[(size_t)n*64+lane]);
}

__global__ __launch_bounds__(192) void k_final(const float* __restrict__ hs, const float* __restrict__ hv,
                                               const float* __restrict__ ht, const int* __restrict__ absorber,
                                               const float* __restrict__ den, const float* __restrict__ cbuf,
                                               const float* __restrict__ Wr1, const float* __restrict__ br1,
                                               const float* __restrict__ Wr2, const float* __restrict__ br2,
                                               float* __restrict__ out, int G){
  __shared__ float zr[176];
  __shared__ float h1[128];
  int g = blockIdx.x, t = threadIdx.x;
  int a = absorber[g];
  if (t < 64) zr[t] = hs[(size_t)a*64+t];
  else if (t < 128){
    int f = t-64;
    zr[t] = cbuf[(size_t)g*64+f] / fmaxf(den[g], 1e-9f);
  } else if (t < 160){
    int j = t-128; float s = 0.f;
    #pragma unroll
    for (int dd=0;dd<3;dd++){ float v = hv[(size_t)a*96+j*3+dd]; s += v*v; }
    zr[t] = s;
  } else if (t < 176){
    int j = t-160; float s = 0.f;
    #pragma unroll
    for (int dd=0;dd<5;dd++){ float v = ht[(size_t)a*80+j*5+dd]; s += v*v; }
    zr[t] = s;
  }
  __syncthreads();
  if (t < 128){
    float acc = br1[t];
    for (int i=0;i<176;i++) acc += zr[i]*Wr1[i*128+t];
    h1[t] = silu_f(acc);
  }
  __syncthreads();
  if (t < 128){
    float acc = br2[t];
    for (int j=0;j<128;j++) acc += h1[j]*Wr2[j*128+t];
    out[(size_t)g*128+t] = acc;
  }
}

extern "C" void kernel_launch(void* const* d_in, const int* in_sizes, int n_in,
                              void* d_out, int out_size, void* d_ws, size_t ws_size,
                              hipStream_t stream){
  const int*   z        = (const int*)  d_in[0];
  const float* pos      = (const float*)d_in[1];
  const int*   ei       = (const int*)  d_in[2];
  const int*   batch    = (const int*)  d_in[3];
  const int*   absorber = (const int*)  d_in[4];
  const float* embed    = (const float*)d_in[5];
  const float* rW1      = (const float*)d_in[6];
  const float* rb1      = (const float*)d_in[7];
  const float* rW2      = (const float*)d_in[8];
  const float* Ws       = (const float*)d_in[9];
  const float* Wss      = (const float*)d_in[10];
  const float* Wv       = (const float*)d_in[11];
  const float* Wvv      = (const float*)d_in[12];
  const float* Wt       = (const float*)d_in[13];
  const float* Wtt      = (const float*)d_in[14];
  const float* Wq       = (const float*)d_in[15];
  const float* Wk       = (const float*)d_in[16];
  const float* Wvp      = (const float*)d_in[17];
  const float* Wr1      = (const float*)d_in[18];
  const float* br1      = (const float*)d_in[19];
  const float* Wr2      = (const float*)d_in[20];
  const float* br2      = (const float*)d_in[21];

  int N = in_sizes[0];
  int E = in_sizes[2]/2;
  int G = in_sizes[4];
  const int* srcArr = ei;
  const int* dstArr = ei + E;

  float* p = (float*)d_ws;
  float* hsA   = p; p += (size_t)N*64;
  float* hvA   = p; p += (size_t)N*96;
  float* htA   = p; p += (size_t)N*80;
  float* hsB   = p; p += (size_t)N*64;
  float* hvB   = p; p += (size_t)N*96;
  float* htB   = p; p += (size_t)N*80;
  float* rb_csr= p; p += (size_t)E*10;
  float* y_csr = p; p += (size_t)E*8;
  unsigned* mkey = (unsigned*)p; p += G;
  float* den   = p; p += G;
  float* cbuf  = p; p += (size_t)G*64;
  int* deg     = (int*)p; p += N;
  int* rowptr  = (int*)p; p += (N+1);
  int* cursor  = (int*)p; p += N;
  int* inv     = (int*)p; p += E;
  int* src_sorted = (int*)p; p += E;
  int* bsum    = (int*)p; p += 256;
  int* boff    = (int*)p; p += 256;
  p += ((8 - (((uintptr_t)p >> 2) & 7)) & 7);   // 32B align
  __half* wgtbuf = (__half*)p;
  float* kbuf    = (float*)wgtbuf;
  float* vbuf    = kbuf + (size_t)N*64;
  float* qbuf    = vbuf + (size_t)N*64;
  float* logitbuf= qbuf + (size_t)G*64;

  int nb = (N + 255)/256;
  int initTot = N*96;
  k_init<<<(initTot+255)/256, 256, 0, stream>>>(z, embed, hsA, hvA, htA, deg, mkey, den, cbuf, N, G);
  k_deg<<<(E+255)/256, 256, 0, stream>>>(dstArr, deg, E);
  k_scanA<<<nb, 256, 0, stream>>>(deg, bsum, N);
  k_scanB<<<1, 256, 0, stream>>>(bsum, boff, nb);
  k_scanC<<<nb, 256, 0, stream>>>(deg, boff, rowptr, cursor, N);
  k_fill<<<(E+255)/256, 256, 0, stream>>>(dstArr, srcArr, cursor, inv, src_sorted, E);
  k_efeat<<<(E+255)/256, 256, 0, stream>>>(pos, srcArr, dstArr, inv, rb_csr, y_csr, E);

  float *hsO=hsA, *hvO=hvA, *htO=htA, *hsN=hsB, *hvN=hvB, *htN=htB;
  for (int l=0; l<NLAYERS; l++){
    k_wgt<<<(E+TILE_E-1)/TILE_E, 320, 0, stream>>>(rb_csr, rW1, rb1, rW2, wgtbuf, E, l);
    k_gather<<<(N+GT_NODES-1)/GT_NODES, 512, 0, stream>>>(hsO, hvO, htO, hsN, hvN, htN,
                                                          rowptr, src_sorted, y_csr, wgtbuf,
                                                          Ws, Wss, Wv, Wvv, Wt, Wtt, N, l);
    float* tp;
    tp=hsO; hsO=hsN; hsN=tp;
    tp=hvO; hvO=hvN; hvN=tp;
    tp=htO; htO=htN; htN=tp;
  }

  k_q<<<G, 64, 0, stream>>>(hsO, absorber, Wq, qbuf, G);
  k_kv<<<(N+7)/8, 64, 0, stream>>>(hsO, Wk, Wvp, kbuf, vbuf, N);
  k_logit<<<(N+3)/4, 256, 0, stream>>>(kbuf, qbuf, batch, logitbuf, mkey, N);
  k_soft<<<(N+3)/4, 256, 0, stream>>>(vbuf, logitbuf, batch, mkey, den, cbuf, N);
  k_final<<<G, 192, 0, stream>>>(hsO, hvO, htO, absorber, den, cbuf, Wr1, br1, Wr2, br2, (float*)d_out, G);
}

// Round 4
// 1619.421 us; speedup vs baseline: 1.2983x; 1.0391x over previous
//
#include <hip/hip_runtime.h>
#include <hip/hip_fp16.h>
#include <cstdint>

#define NLAYERS 4
#define TILE_E 32
#define GCHUNK 14

__device__ __forceinline__ float silu_f(float x){ return x / (1.f + __expf(-x)); }

// ---------------- init ----------------
__global__ void k_init(const int* __restrict__ z, const float* __restrict__ embed,
                       float* __restrict__ hs, float* __restrict__ hv, float* __restrict__ ht,
                       int* __restrict__ deg,
                       unsigned* __restrict__ mkey, float* __restrict__ den, float* __restrict__ cbuf,
                       int N, int G){
  int idx = blockIdx.x*blockDim.x + threadIdx.x;
  if (idx < N*64) hs[idx] = embed[z[idx>>6]*64 + (idx&63)];
  if (idx < N*96) hv[idx] = 0.f;
  if (idx < N*80) ht[idx] = 0.f;
  if (idx < N)   deg[idx] = 0;
  if (idx < G) { mkey[idx] = 0u; den[idx] = 0.f; }
  if (idx < G*64) cbuf[idx] = 0.f;
}

// ---------------- CSR build ----------------
__global__ void k_deg(const int* __restrict__ dst, int* __restrict__ deg, int E){
  int e = blockIdx.x*blockDim.x + threadIdx.x;
  if (e < E) atomicAdd(&deg[dst[e]], 1);
}

__global__ __launch_bounds__(256) void k_scanA(const int* __restrict__ deg, int* __restrict__ bsum, int N){
  __shared__ int red[256];
  int t = threadIdx.x;
  int idx = blockIdx.x*256 + t;
  red[t] = (idx < N) ? deg[idx] : 0;
  __syncthreads();
  for (int off=128; off>0; off>>=1){ if (t<off) red[t] += red[t+off]; __syncthreads(); }
  if (t==0) bsum[blockIdx.x] = red[0];
}

__global__ __launch_bounds__(256) void k_scanB(const int* __restrict__ bsum, int* __restrict__ boff, int nb){
  __shared__ int s[256];
  int t = threadIdx.x;
  s[t] = (t < nb) ? bsum[t] : 0;
  __syncthreads();
  for (int off=1; off<256; off<<=1){
    int v = (t>=off) ? s[t-off] : 0;
    __syncthreads();
    s[t] += v;
    __syncthreads();
  }
  if (t < nb) boff[t] = (t==0) ? 0 : s[t-1];
}

__global__ __launch_bounds__(256) void k_scanC(const int* __restrict__ deg, const int* __restrict__ boff,
                                               int* __restrict__ rowptr, int* __restrict__ cursor, int N){
  __shared__ int s[256];
  int t = threadIdx.x;
  int idx = blockIdx.x*256 + t;
  int v = (idx < N) ? deg[idx] : 0;
  s[t] = v;
  __syncthreads();
  for (int off=1; off<256; off<<=1){
    int u = (t>=off) ? s[t-off] : 0;
    __syncthreads();
    s[t] += u;
    __syncthreads();
  }
  int base = boff[blockIdx.x];
  if (idx < N){
    int ex = base + s[t] - v;
    rowptr[idx] = ex;
    cursor[idx] = ex;
    if (idx == N-1) rowptr[N] = base + s[t];
  }
}

__global__ void k_fill(const int* __restrict__ dst, const int* __restrict__ src,
                       int* __restrict__ cursor, int* __restrict__ inv, int* __restrict__ src_sorted, int E){
  int e = blockIdx.x*blockDim.x + threadIdx.x;
  if (e < E){
    int p = atomicAdd(&cursor[dst[e]], 1);
    inv[e] = p;
    src_sorted[p] = src[e];
  }
}

// ---------------- edge features in CSR order ----------------
__global__ void k_efeat(const float* __restrict__ pos, const int* __restrict__ src,
                        const int* __restrict__ dst, const int* __restrict__ inv,
                        float* __restrict__ rb_csr, float* __restrict__ y_csr, int E){
  int e = blockIdx.x*blockDim.x + threadIdx.x;
  if (e >= E) return;
  int s = src[e], d = dst[e];
  int j = inv[e];
  float vx = pos[d*3+0]-pos[s*3+0];
  float vy = pos[d*3+1]-pos[s*3+1];
  float vz = pos[d*3+2]-pos[s*3+2];
  float elen = sqrtf(vx*vx+vy*vy+vz*vz);
  float iv = 1.f/(elen+1e-9f);
  float x = vx*iv, y = vy*iv, zc = vz*iv;
  const float s3 = 1.7320508075688772f, s5 = 2.2360679774997896f, s15 = 3.872983346207417f;
  float* yp = y_csr + (size_t)j*8;   // Y1..Y8 (Y0==1 implicit)
  yp[0] = s3*x;  yp[1] = s3*y;  yp[2] = s3*zc;
  yp[3] = s15*x*y; yp[4] = s15*y*zc;
  yp[5] = 0.5f*s5*(3.f*zc*zc-1.f);
  yp[6] = s15*x*zc; yp[7] = 0.5f*s15*(x*x-y*y);
  const float sigma = 5.0f/9.0f;
  float* rp = rb_csr + (size_t)j*10;
  #pragma unroll
  for (int k=0;k<10;k++){
    float c = (5.0f/9.0f)*(float)k;
    float tt = (elen - c)/sigma;
    rp[k] = __expf(-0.5f*tt*tt);
  }
}

// ---------------- k_wgt: radial weights in CSR order, fp16 ----------------
__global__ __launch_bounds__(320) void k_wgt(
    const float* __restrict__ rb_csr,
    const float* __restrict__ rW1, const float* __restrict__ rb1, const float* __restrict__ rW2,
    __half* __restrict__ wgtbuf, int E, int l)
{
  __shared__ float hid[TILE_E][32];
  int t = threadIdx.x;
  int j0 = blockIdx.x*TILE_E;

  for (int idx=t; idx<TILE_E*32; idx+=320){
    int el = idx>>5, jj = idx&31;
    int j = j0+el;
    if (j < E){
      float acc = rb1[l*32+jj];
      const float* rbp = rb_csr + (size_t)j*10;
      const float* w1p = rW1 + (l*10)*32 + jj;
      #pragma unroll
      for (int k=0;k<10;k++) acc += rbp[k]*w1p[k*32];
      hid[el][jj] = silu_f(acc);
    }
  }
  float wcol[32];
  {
    const float* w2p = rW2 + (size_t)(l*32)*320 + t;
    #pragma unroll
    for (int jj=0;jj<32;jj++) wcol[jj] = w2p[(size_t)jj*320];
  }
  __syncthreads();

  for (int el=0; el<TILE_E; el++){
    int j = j0+el;
    if (j >= E) break;
    const float4* hrow = (const float4*)hid[el];
    float a0=0.f,a1=0.f,a2=0.f,a3=0.f;
    #pragma unroll
    for (int q=0;q<8;q++){
      float4 h4 = hrow[q];
      a0 += h4.x*wcol[q*4+0];
      a1 += h4.y*wcol[q*4+1];
      a2 += h4.z*wcol[q*4+2];
      a3 += h4.w*wcol[q*4+3];
    }
    wgtbuf[(size_t)j*320 + t] = __float2half((a0+a1)+(a2+a3));
  }
}

// ---------------- k_gather: block per node, thread per component ----------------
// comp layout: [0,112) a0, [112,496) a1 (row*3+dd), [496,896) a2 (row*5+dd)
// src-row LDS layout: [0,64) s, [64,160) v, [160,240) t
__global__ __launch_bounds__(896) void k_gather(
    const float* __restrict__ hs0, const float* __restrict__ hv0, const float* __restrict__ ht0,
    float* __restrict__ hs1, float* __restrict__ hv1, float* __restrict__ ht1,
    const int* __restrict__ rowptr, const int* __restrict__ src_sorted,
    const float* __restrict__ y_csr, const __half* __restrict__ wgtbuf,
    const float* __restrict__ Ws, const float* __restrict__ Wss,
    const float* __restrict__ Wv, const float* __restrict__ Wvv,
    const float* __restrict__ Wt, const float* __restrict__ Wtt,
    int N, int l)
{
  __shared__ float sF[GCHUNK][240];
  __shared__ float sY[GCHUNK][10];    // [8]=1, [9]=0
  int t = threadIdx.x;
  int w = t>>6, lane = t&63;
  int n = blockIdx.x;
  int rs = rowptr[n], re = rowptr[n+1];

  // ---- per-thread component mapping (computed once) ----
  int c = t;
  int special = 0;        // 0 general, 2 dot3, 3 dot5
  int widx, off0, off1 = 0, ds0 = 8, ds1 = 9;   // default: *1, -*0
  if (c < 64){            // a0 scalar
    widx = c; off0 = c; off1 = off0;
  } else if (c < 96){     // a0 vec dot Y1..3
    special = 2; widx = c; off0 = 64 + (c-64)*3;
  } else if (c < 112){    // a0 tensor dot Y4..8
    special = 3; widx = c; off0 = 160 + (c-96)*5;
  } else if (c < 496){
    int rr = c-112, row = rr/3, dd = rr - row*3;
    if (row < 64){        // w1s * s * Y(1+dd)
      widx = 112+row; off0 = row; off1 = off0; ds0 = dd;
    } else if (row < 96){ // w1v * v
      widx = 176+(row-64); off0 = 64+(row-64)*3+dd; off1 = off0;
    } else {              // w1x * cross(v, y)
      int cc = row-96;
      int d1 = dd+1; if (d1>2) d1-=3;
      int d2 = dd+2; if (d2>2) d2-=3;
      widx = 208+cc; off0 = 64+cc*3+d1; ds0 = d2; off1 = 64+cc*3+d2; ds1 = d1;
    }
  } else {
    int rr = c-496, row = rr/5, dd = rr - row*5;
    if (row < 64){        // w2s * s * Y(4+dd)
      widx = 240+row; off0 = row; off1 = off0; ds0 = 3+dd;
    } else {              // w2t * t
      widx = 304+(row-64); off0 = 160+(row-64)*5+dd; off1 = off0;
    }
  }

  float r = 0.f;
  for (int ch = rs; ch < re; ch += GCHUNK){
    int cnt = min(GCHUNK, re-ch);
    if (w < cnt){
      int j = ch + w;
      int s_ = src_sorted[j];
      #pragma unroll
      for (int q = 0; q < 4; q++){
        int idx = lane + q*64;
        if (idx < 240){
          float v;
          if (idx < 64)       v = hs0[(size_t)s_*64 + idx];
          else if (idx < 160) v = hv0[(size_t)s_*96 + (idx-64)];
          else                v = ht0[(size_t)s_*80 + (idx-160)];
          sF[w][idx] = v;
        }
      }
      if (lane < 10) sY[w][lane] = (lane < 8) ? y_csr[(size_t)j*8 + lane] : (lane==8 ? 1.f : 0.f);
    }
    __syncthreads();
    if (special == 0){
      for (int jj=0; jj<cnt; jj++){
        float wg = __half2float(wgtbuf[(size_t)(ch+jj)*320 + widx]);
        r += wg * (sF[jj][off0]*sY[jj][ds0] - sF[jj][off1]*sY[jj][ds1]);
      }
    } else if (special == 2){
      for (int jj=0; jj<cnt; jj++){
        float wg = __half2float(wgtbuf[(size_t)(ch+jj)*320 + widx]);
        r += wg * (sF[jj][off0]*sY[jj][0] + sF[jj][off0+1]*sY[jj][1] + sF[jj][off0+2]*sY[jj][2]);
      }
    } else {
      for (int jj=0; jj<cnt; jj++){
        float wg = __half2float(wgtbuf[(size_t)(ch+jj)*320 + widx]);
        r += wg * (sF[jj][off0]*sY[jj][3] + sF[jj][off0+1]*sY[jj][4] + sF[jj][off0+2]*sY[jj][5]
                 + sF[jj][off0+3]*sY[jj][6] + sF[jj][off0+4]*sY[jj][7]);
      }
    }
    __syncthreads();
  }

  // park accumulators in LDS (reuse sF) for the update phase
  float* accL = &sF[0][0];
  accL[c] = r;
  __syncthreads();

  // ---- fused node update for node n ----
  if (t < 64){
    int f = t;
    float acc_ = 0.f;
    const float* WsL  = Ws  + (size_t)l*112*64;
    const float* WssL = Wss + (size_t)l*64*64;
    const float* hrow = hs0 + (size_t)n*64;
    for (int cc=0; cc<112; cc++) acc_ += accL[cc]*WsL[cc*64+f];
    for (int cc=0; cc<64;  cc++) acc_ += hrow[cc]*WssL[cc*64+f];
    hs1[(size_t)n*64+f] = silu_f(acc_);
  } else if (t < 160){
    int rr = t-64, f = rr/3, dd = rr - f*3;
    float acc_ = 0.f;
    const float* WvL  = Wv  + (size_t)l*128*32;
    const float* WvvL = Wvv + (size_t)l*32*32;
    const float* vrow = hv0 + (size_t)n*96;
    for (int cc=0; cc<128; cc++) acc_ += accL[112+cc*3+dd]*WvL[cc*32+f];
    for (int cc=0; cc<32;  cc++) acc_ += vrow[cc*3+dd]*WvvL[cc*32+f];
    hv1[(size_t)n*96+f*3+dd] = acc_;
  } else if (t < 240){
    int rr = t-160, f = rr/5, dd = rr - f*5;
    float acc_ = 0.f;
    const float* WtL  = Wt  + (size_t)l*80*16;
    const float* WttL = Wtt + (size_t)l*16*16;
    const float* trow = ht0 + (size_t)n*80;
    for (int cc=0; cc<80; cc++) acc_ += accL[496+cc*5+dd]*WtL[cc*16+f];
    for (int cc=0; cc<16; cc++) acc_ += trow[cc*5+dd]*WttL[cc*16+f];
    ht1[(size_t)n*80+f*5+dd] = acc_;
  }
}

// ---------------- readout ----------------
__global__ __launch_bounds__(64) void k_q(const float* __restrict__ hs, const int* __restrict__ absorber,
                                          const float* __restrict__ Wq, float* __restrict__ qbuf, int G){
  __shared__ float sH[64];
  int g = blockIdx.x, f = threadIdx.x;
  int a = absorber[g];
  sH[f] = hs[(size_t)a*64+f];
  __syncthreads();
  float acc = 0.f;
  for (int c=0;c<64;c++) acc += sH[c]*Wq[c*64+f];
  qbuf[(size_t)g*64+f] = acc;
}

__global__ __launch_bounds__(64) void k_kv(const float* __restrict__ hs,
                                           const float* __restrict__ Wk, const float* __restrict__ Wvp,
                                           float* __restrict__ kbuf, float* __restrict__ vbuf, int N){
  __shared__ float sH[8][64];
  int t = threadIdx.x;
  int n0 = blockIdx.x*8;
  int nmax = min(8, N-n0);
  for (int idx=t; idx<nmax*64; idx+=64){ int n=idx>>6, c=idx&63; sH[n][c]=hs[(size_t)(n0+n)*64+c]; }
  __syncthreads();
  float ka[8], va[8];
  #pragma unroll
  for (int n=0;n<8;n++){ ka[n]=0.f; va[n]=0.f; }
  for (int c=0;c<64;c++){
    float wk = Wk[c*64+t], wv = Wvp[c*64+t];
    #pragma unroll
    for (int n=0;n<8;n++){ ka[n]+=sH[n][c]*wk; va[n]+=sH[n][c]*wv; }
  }
  for (int n=0;n<nmax;n++){ kbuf[(size_t)(n0+n)*64+t]=ka[n]; vbuf[(size_t)(n0+n)*64+t]=va[n]; }
}

__global__ __launch_bounds__(256) void k_logit(const float* __restrict__ kbuf, const float* __restrict__ qbuf,
                                               const int* __restrict__ batch,
                                               float* __restrict__ logitbuf, unsigned* __restrict__ mkey, int N){
  int wave = threadIdx.x>>6, lane = threadIdx.x&63;
  int n = blockIdx.x*4 + wave;
  if (n >= N) return;
  int g = batch[n];
  float p = kbuf[(size_t)n*64+lane]*qbuf[(size_t)g*64+lane];
  #pragma unroll
  for (int off=32; off>0; off>>=1) p += __shfl_down(p, off, 64);
  if (lane==0){
    float logit = p*0.125f;
    logitbuf[n] = logit;
    unsigned u = __float_as_uint(logit);
    unsigned key = (u & 0x80000000u) ? ~u : (u | 0x80000000u);
    atomicMax(&mkey[g], key);
  }
}

__global__ __launch_bounds__(256) void k_soft(const float* __restrict__ vbuf, const float* __restrict__ logitbuf,
                                              const int* __restrict__ batch, const unsigned* __restrict__ mkey,
                                              float* __restrict__ den, float* __restrict__ cbuf, int N){
  int wave = threadIdx.x>>6, lane = threadIdx.x&63;
  int n = blockIdx.x*4 + wave;
  if (n >= N) return;
  int g = batch[n];
  unsigned key = mkey[g];
  unsigned u = (key & 0x80000000u) ? (key ^ 0x80000000u) : ~key;
  float m = __uint_as_float(u);
  float ex = __expf(logitbuf[n] - m);
  if (lane==0) atomicAdd(&den[g], ex);
  atomicAdd(&cbuf[(size_t)g*64+lane], ex*vbuf[(size_t)n*64+lane]);
}

__global__ __launch_bounds__(192) void k_final(const float* __restrict__ hs, const float* __restrict__ hv,
                                               const float* __restrict__ ht, const int* __restrict__ absorber,
                                               const float* __restrict__ den, const float* __restrict__ cbuf,
                                               const float* __restrict__ Wr1, const float* __restrict__ br1,
                                               const float* __restrict__ Wr2, const float* __restrict__ br2,
                                               float* __restrict__ out, int G){
  __shared__ float zr[176];
  __shared__ float h1[128];
  int g = blockIdx.x, t = threadIdx.x;
  int a = absorber[g];
  if (t < 64) zr[t] = hs[(size_t)a*64+t];
  else if (t < 128){
    int f = t-64;
    zr[t] = cbuf[(size_t)g*64+f] / fmaxf(den[g], 1e-9f);
  } else if (t < 160){
    int j = t-128; float s = 0.f;
    #pragma unroll
    for (int dd=0;dd<3;dd++){ float v = hv[(size_t)a*96+j*3+dd]; s += v*v; }
    zr[t] = s;
  } else if (t < 176){
    int j = t-160; float s = 0.f;
    #pragma unroll
    for (int dd=0;dd<5;dd++){ float v = ht[(size_t)a*80+j*5+dd]; s += v*v; }
    zr[t] = s;
  }
  __syncthreads();
  if (t < 128){
    float acc = br1[t];
    for (int i=0;i<176;i++) acc += zr[i]*Wr1[i*128+t];
    h1[t] = silu_f(acc);
  }
  __syncthreads();
  if (t < 128){
    float acc = br2[t];
    for (int j=0;j<128;j++) acc += h1[j]*Wr2[j*128+t];
    out[(size_t)g*128+t] = acc;
  }
}

extern "C" void kernel_launch(void* const* d_in, const int* in_sizes, int n_in,
                              void* d_out, int out_size, void* d_ws, size_t ws_size,
                              hipStream_t stream){
  const int*   z        = (const int*)  d_in[0];
  const float* pos      = (const float*)d_in[1];
  const int*   ei       = (const int*)  d_in[2];
  const int*   batch    = (const int*)  d_in[3];
  const int*   absorber = (const int*)  d_in[4];
  const float* embed    = (const float*)d_in[5];
  const float* rW1      = (const float*)d_in[6];
  const float* rb1      = (const float*)d_in[7];
  const float* rW2      = (const float*)d_in[8];
  const float* Ws       = (const float*)d_in[9];
  const float* Wss      = (const float*)d_in[10];
  const float* Wv       = (const float*)d_in[11];
  const float* Wvv      = (const float*)d_in[12];
  const float* Wt       = (const float*)d_in[13];
  const float* Wtt      = (const float*)d_in[14];
  const float* Wq       = (const float*)d_in[15];
  const float* Wk       = (const float*)d_in[16];
  const float* Wvp      = (const float*)d_in[17];
  const float* Wr1      = (const float*)d_in[18];
  const float* br1      = (const float*)d_in[19];
  const float* Wr2      = (const float*)d_in[20];
  const float* br2      = (const float*)d_in[21];

  int N = in_sizes[0];
  int E = in_sizes[2]/2;
  int G = in_sizes[4];
  const int* srcArr = ei;
  const int* dstArr = ei + E;

  float* p = (float*)d_ws;
  float* hsA   = p; p += (size_t)N*64;
  float* hvA   = p; p += (size_t)N*96;
  float* htA   = p; p += (size_t)N*80;
  float* hsB   = p; p += (size_t)N*64;
  float* hvB   = p; p += (size_t)N*96;
  float* htB   = p; p += (size_t)N*80;
  float* rb_csr= p; p += (size_t)E*10;
  float* y_csr = p; p += (size_t)E*8;
  unsigned* mkey = (unsigned*)p; p += G;
  float* den   = p; p += G;
  float* cbuf  = p; p += (size_t)G*64;
  int* deg     = (int*)p; p += N;
  int* rowptr  = (int*)p; p += (N+1);
  int* cursor  = (int*)p; p += N;
  int* inv     = (int*)p; p += E;
  int* src_sorted = (int*)p; p += E;
  int* bsum    = (int*)p; p += 256;
  int* boff    = (int*)p; p += 256;
  p += ((8 - (((uintptr_t)p >> 2) & 7)) & 7);   // 32B align
  __half* wgtbuf = (__half*)p;
  float* kbuf    = (float*)wgtbuf;
  float* vbuf    = kbuf + (size_t)N*64;
  float* qbuf    = vbuf + (size_t)N*64;
  float* logitbuf= qbuf + (size_t)G*64;

  int nb = (N + 255)/256;
  int initTot = N*96;
  k_init<<<(initTot+255)/256, 256, 0, stream>>>(z, embed, hsA, hvA, htA, deg, mkey, den, cbuf, N, G);
  k_deg<<<(E+255)/256, 256, 0, stream>>>(dstArr, deg, E);
  k_scanA<<<nb, 256, 0, stream>>>(deg, bsum, N);
  k_scanB<<<1, 256, 0, stream>>>(bsum, boff, nb);
  k_scanC<<<nb, 256, 0, stream>>>(deg, boff, rowptr, cursor, N);
  k_fill<<<(E+255)/256, 256, 0, stream>>>(dstArr, srcArr, cursor, inv, src_sorted, E);
  k_efeat<<<(E+255)/256, 256, 0, stream>>>(pos, srcArr, dstArr, inv, rb_csr, y_csr, E);

  float *hsO=hsA, *hvO=hvA, *htO=htA, *hsN=hsB, *hvN=hvB, *htN=htB;
  for (int l=0; l<NLAYERS; l++){
    k_wgt<<<(E+TILE_E-1)/TILE_E, 320, 0, stream>>>(rb_csr, rW1, rb1, rW2, wgtbuf, E, l);
    k_gather<<<N, 896, 0, stream>>>(hsO, hvO, htO, hsN, hvN, htN,
                                    rowptr, src_sorted, y_csr, wgtbuf,
                                    Ws, Wss, Wv, Wvv, Wt, Wtt, N, l);
    float* tp;
    tp=hsO; hsO=hsN; hsN=tp;
    tp=hvO; hvO=hvN; hvN=tp;
    tp=htO; htO=htN; htN=tp;
  }

  k_q<<<G, 64, 0, stream>>>(hsO, absorber, Wq, qbuf, G);
  k_kv<<<(N+7)/8, 64, 0, stream>>>(hsO, Wk, Wvp, kbuf, vbuf, N);
  k_logit<<<(N+3)/4, 256, 0, stream>>>(kbuf, qbuf, batch, logitbuf, mkey, N);
  k_soft<<<(N+3)/4, 256, 0, stream>>>(vbuf, logitbuf, batch, mkey, den, cbuf, N);
  k_final<<<G, 192, 0, stream>>>(hsO, hvO, htO, absorber, den, cbuf, Wr1, br1, Wr2, br2, (float*)d_out, G);
}